// Round 11
// baseline (254.618 us; speedup 1.0000x reference)
//
#include <hip/hip_runtime.h>
#include <hip/hip_bf16.h>
#include <math.h>

#define NVOX   884736      // 96^3 per batch
#define NBINS  64
#define NCHUNK 27648       // NVOX / 32
#define GX     512         // 1024 blocks total = 4 blocks/CU (4 waves/SIMD), 1 round
#define NWAVETOT (GX*4)    // 2048 waves/batch -> 13 or 14 chunks each (ragged, R4 partition)
#define EPSF   1e-8f

// w = exp(-0.5*((xn-c)/sigma)^2) = exp2(-(A*xn - A*c)^2),  A = sqrt(0.5*log2(e))/sigma
#define A_SC  8.49321957f
#define ABIN  (A_SC/63.0f)

// fixed-point scale for deterministic integer accumulation
#define FSCALE 1073741824.0f   // 2^30
#define DSCALE (1.0/1073741824.0)

typedef __attribute__((ext_vector_type(8))) short short8;
typedef __attribute__((ext_vector_type(4))) float f32x4;
typedef unsigned long long u64;

#define EXP2(x) __builtin_amdgcn_exp2f(x)

#define NJ64 8448   // 2*4096 J + 2*64 PF + 2*64 PW

__device__ __forceinline__ short tobf(float w){
  __bf16 hb = (__bf16)w;
  return __builtin_bit_cast(short, hb);
}

// ---- k_minmax: exact per-block min/max partials (no atomics, no init) + zero u64 region ----
__global__ __launch_bounds__(256) void k_minmax(const float* __restrict__ fixed_,
                                                const float* __restrict__ warped_,
                                                float* __restrict__ pmn,
                                                float* __restrict__ pmx,
                                                u64* __restrict__ w64){
  const int slot = blockIdx.y;                 // img*2 + b
  const int tid  = threadIdx.x;
  if (slot == 0){
    int gid = blockIdx.x*256 + tid;            // 128*256 = 32768 >= 8448
    if (gid < NJ64) w64[gid] = 0ull;
  }
  const float* p = ((slot & 2) ? warped_ : fixed_) + (slot & 1) * NVOX;
  const float4* p4 = (const float4*)p;
  const int n4 = NVOX/4;
  float lo = 3.4e38f, hi = -3.4e38f;
  for (int i = blockIdx.x*256 + tid; i < n4; i += 128*256){
    float4 v = p4[i];
    lo = fminf(lo, fminf(fminf(v.x,v.y), fminf(v.z,v.w)));
    hi = fmaxf(hi, fmaxf(fmaxf(v.x,v.y), fmaxf(v.z,v.w)));
  }
  #pragma unroll
  for (int d = 1; d < 64; d <<= 1){
    lo = fminf(lo, __shfl_xor(lo, d));
    hi = fmaxf(hi, __shfl_xor(hi, d));
  }
  __shared__ float smn[4], smx[4];
  if ((tid & 63) == 0){ smn[tid>>6] = lo; smx[tid>>6] = hi; }
  __syncthreads();
  if (tid == 0){
    pmn[slot*128 + blockIdx.x] = fminf(fminf(smn[0],smn[1]), fminf(smn[2],smn[3]));
    pmx[slot*128 + blockIdx.x] = fmaxf(fmaxf(smx[0],smx[1]), fmaxf(smx[2],smx[3]));
  }
}

// S-loop: FROZEN R4/R5/R9/R10 numerics (t first, then square; 4 independent partials)
__device__ __forceinline__ void s_and_lg(float u, float H, float& lg){
  float S0=0.f, S1=0.f, S2=0.f, S3=0.f;
  #pragma unroll
  for (int k = 0; k < 64; k += 4){
    float t0 = u - (float)(k+0)*H; S0 += EXP2(-(t0*t0));
    float t1 = u - (float)(k+1)*H; S1 += EXP2(-(t1*t1));
    float t2 = u - (float)(k+2)*H; S2 += EXP2(-(t2*t2));
    float t3 = u - (float)(k+3)*H; S3 += EXP2(-(t3*t3));
  }
  const float S = (S0+S1)+(S2+S3);
  lg = -__builtin_amdgcn_logf(S + EPSF);  // log2(1/(S+eps))
}

__global__ __launch_bounds__(256, 4) void k_main(const float* __restrict__ fx0,
                                                 const float* __restrict__ wx0,
                                                 u64* __restrict__ J64,
                                                 u64* __restrict__ PF64,
                                                 u64* __restrict__ PW64,
                                                 const float* __restrict__ pmn,
                                                 const float* __restrict__ pmx){
  const int b    = blockIdx.y;
  const int lane = threadIdx.x & 63;
  const int wid  = threadIdx.x >> 6;
  const int r    = lane & 15;       // bin-within-quadrant (A row / B col)
  const int g    = lane >> 4;       // k-group: voxels 8g..8g+7

  // per-lane min/max from 128 exact partials (lanes 0-31: fixed, 32-63: warped)
  const int hl = lane & 31;
  const int sbase = ((lane >> 5)*2 + b) * 128;
  float lo = fminf(fminf(pmn[sbase+hl], pmn[sbase+32+hl]),
                   fminf(pmn[sbase+64+hl], pmn[sbase+96+hl]));
  float hi = fmaxf(fmaxf(pmx[sbase+hl], pmx[sbase+32+hl]),
                   fmaxf(pmx[sbase+64+hl], pmx[sbase+96+hl]));
  #pragma unroll
  for (int d = 1; d < 32; d <<= 1){           // reduce within each 32-lane half
    lo = fminf(lo, __shfl_xor(lo, d));
    hi = fmaxf(hi, __shfl_xor(hi, d));
  }
  const float mn = lo;
  const float sc = A_SC / (hi - lo + EPSF);

  const float H = ABIN;
  float CQ[4];
  #pragma unroll
  for (int q = 0; q < 4; q++) CQ[q] = (float)(16*q + r) * H;

  f32x4 acc[4][4];
  #pragma unroll
  for (int q = 0; q < 4; q++)
    #pragma unroll
    for (int t = 0; t < 4; t++)
      acc[q][t] = (f32x4){0.f,0.f,0.f,0.f};
  float pfa[4] = {0.f,0.f,0.f,0.f}, pwa[4] = {0.f,0.f,0.f,0.f};

  const float* fx = fx0 + b*NVOX;
  const float* wx = wx0 + b*NVOX;
  const float* src = (lane < 32) ? fx : (wx - 32);
  const int gwave = blockIdx.x*4 + wid;
  const int base0 = gwave*32 + lane;   // chunk stride = NWAVETOT*32 = 65536 elements

  // per-wave LDS scratch for (u, lg) cross-lane distribution (broadcast reads)
  __shared__ float2 sUL[4][64];
  float2* ul = sUL[wid];

  // ---- prologue: chunk gwave current state, chunk gwave+NWAVETOT raw prefetched ----
  float u_c, lg_c;
  {
    float x0 = src[base0];
    u_c = (x0 - mn) * sc;
    s_and_lg(u_c, H, lg_c);
  }
  float x_n = 0.f;
  if (gwave + NWAVETOT < NCHUNK) x_n = src[base0 + NWAVETOT*32];

  #pragma unroll 1
  for (int c = gwave; c < NCHUNK; c += NWAVETOT){
    short8 Af[4], Bf[4];
    float u_n, lg_n, x_n2;

    // ---- publish own (u,lg); read half-0 pairs (voxels 8g..8g+3; broadcast) ----
    ul[lane] = (float2){u_c, lg_c};            // same-wave DS: in-order, no barrier
    float2 pf0[4], pw0[4];
    #pragma unroll
    for (int i = 0; i < 4; i++){
      pf0[i] = ul[8*g + i];
      pw0[i] = ul[32 + 8*g + i];
    }

    // ---- overlap: 2-ahead raw prefetch + next-chunk S while LDS reads fly ----
    const int cn = c + NWAVETOT;
    if (cn + NWAVETOT < NCHUNK) x_n2 = src[base0 + (c - gwave + 2*NWAVETOT)*32];
    if (cn < NCHUNK){
      u_n = (x_n - mn) * sc;
      s_and_lg(u_n, H, lg_n);
    }

    // ---- consume half 0: FROZEN weight form, order (i asc, q inner) ----
    #pragma unroll
    for (int i = 0; i < 4; i++){
      #pragma unroll
      for (int q = 0; q < 4; q++){
        float ta = pf0[i].x - CQ[q];
        float wa = EXP2(__builtin_fmaf(-ta, ta, pf0[i].y));
        pfa[q] += wa;  Af[q][i] = tobf(wa);
        float tb = pw0[i].x - CQ[q];
        float wb = EXP2(__builtin_fmaf(-tb, tb, pw0[i].y));
        pwa[q] += wb;  Bf[q][i] = tobf(wb);
      }
    }

    // ---- half 1: read pairs (voxels 8g+4..8g+7), consume ----
    #pragma unroll
    for (int i = 0; i < 4; i++){
      pf0[i] = ul[8*g + 4 + i];
      pw0[i] = ul[32 + 8*g + 4 + i];
    }
    #pragma unroll
    for (int i = 0; i < 4; i++){
      #pragma unroll
      for (int q = 0; q < 4; q++){
        float ta = pf0[i].x - CQ[q];
        float wa = EXP2(__builtin_fmaf(-ta, ta, pf0[i].y));
        pfa[q] += wa;  Af[q][4+i] = tobf(wa);
        float tb = pw0[i].x - CQ[q];
        float wb = EXP2(__builtin_fmaf(-tb, tb, pw0[i].y));
        pwa[q] += wb;  Bf[q][4+i] = tobf(wb);
      }
    }

    // ---- 16 MFMAs ----
    #pragma unroll
    for (int q = 0; q < 4; q++)
      #pragma unroll
      for (int qq = 0; qq < 4; qq++)
        acc[q][qq] = __builtin_amdgcn_mfma_f32_16x16x32_bf16(Af[q], Bf[qq], acc[q][qq], 0, 0, 0);

    u_c = u_n; lg_c = lg_n; x_n = x_n2;
  }

  // marginals: shuffle-reduce (deterministic), lanes 0-15 commit as u64 fixed-point
  #pragma unroll
  for (int q = 0; q < 4; q++){
    pfa[q] += __shfl_xor(pfa[q], 16); pfa[q] += __shfl_xor(pfa[q], 32);
    pwa[q] += __shfl_xor(pwa[q], 16); pwa[q] += __shfl_xor(pwa[q], 32);
  }
  if (lane < 16){
    #pragma unroll
    for (int q = 0; q < 4; q++){
      long long vf = __builtin_llrintf(pfa[q] * FSCALE);
      long long vw = __builtin_llrintf(pwa[q] * FSCALE);
      atomicAdd(&PF64[b*64 + 16*q + r], (u64)vf);
      atomicAdd(&PW64[b*64 + 16*q + r], (u64)vw);
    }
  }

  // joint: deterministic block reduce — waves accumulate into jl in FIXED order
  __shared__ float jl[64*64];
  // C/D layout (m89-verified): col = lane&15, row = (lane>>4)*4 + reg
  #pragma unroll
  for (int w2 = 0; w2 < 4; w2++){
    if (wid == w2){
      #pragma unroll
      for (int q = 0; q < 4; q++)
        #pragma unroll
        for (int qq = 0; qq < 4; qq++)
          #pragma unroll
          for (int j = 0; j < 4; j++){
            int idx = (16*q + 4*g + j)*64 + 16*qq + r;
            float v = acc[q][qq][j];
            jl[idx] = (w2 == 0) ? v : (jl[idx] + v);
          }
    }
    __syncthreads();
  }
  // convert to u64 fixed-point, order-independent global accumulation
  for (int i = threadIdx.x; i < 4096; i += 256){
    long long v = __builtin_llrintf(jl[i] * FSCALE);
    if (v) atomicAdd(&J64[b*4096 + i], (u64)v);
  }
}

// ---- k_final: both batches in parallel half-blocks; fp64 accumulate, f32-ratio + hw log ----
__global__ __launch_bounds__(1024) void k_final(const u64* __restrict__ J64,
                                                const u64* __restrict__ PF64,
                                                const u64* __restrict__ PW64,
                                                float* out){
  __shared__ double red[1024];
  const int tid = threadIdx.x;
  const int b   = tid >> 9;          // threads 0-511: batch 0; 512-1023: batch 1
  const int t5  = tid & 511;
  const double invN = 1.0 / (double)NVOX;
  const u64* J  = J64  + b*4096;
  const u64* PF = PF64 + b*64;
  const u64* PW = PW64 + b*64;

  double ts = 0.0;
  for (int i = t5; i < 4096; i += 512) ts += (double)J[i];
  red[tid] = ts; __syncthreads();
  #pragma unroll
  for (int s = 256; s > 0; s >>= 1){ if (t5 < s) red[tid] += red[tid+s]; __syncthreads(); }
  const double tot = red[b << 9] * DSCALE * invN;
  const double cj  = DSCALE * invN / (tot + 1e-8);
  __syncthreads();

  double part = 0.0;
  for (int i = t5; i < 4096; i += 512){
    int k = i >> 6, l = i & 63;
    double pj = (double)J[i] * cj;
    double pp = ((double)PF[k] * DSCALE * invN) * ((double)PW[l] * DSCALE * invN);
    float ratio = (float)((pj + 1e-8) / (pp + 1e-8));
    part += pj * (0.6931471805599453 * (double)__builtin_amdgcn_logf(ratio));
  }
  red[tid] = part; __syncthreads();
  #pragma unroll
  for (int s = 256; s > 0; s >>= 1){ if (t5 < s) red[tid] += red[tid+s]; __syncthreads(); }
  if (tid == 0) out[0] = (float)(-((red[0] + red[512]) * 0.5));
}

extern "C" void kernel_launch(void* const* d_in, const int* in_sizes, int n_in,
                              void* d_out, int out_size, void* d_ws, size_t ws_size,
                              hipStream_t stream) {
  const float* fixed_  = (const float*)d_in[0];
  const float* warped_ = (const float*)d_in[1];
  u64*   w64  = (u64*)d_ws;
  u64*   J64  = w64;              // 2*4096
  u64*   PF64 = w64 + 8192;       // 2*64
  u64*   PW64 = w64 + 8320;       // 2*64
  float* pmn  = (float*)((char*)d_ws + NJ64*8);   // 4*128 floats
  float* pmx  = pmn + 512;
  float* out  = (float*)d_out;

  hipLaunchKernelGGL(k_minmax, dim3(128, 4), dim3(256),  0, stream, fixed_, warped_, pmn, pmx, w64);
  hipLaunchKernelGGL(k_main,   dim3(GX, 2),  dim3(256),  0, stream, fixed_, warped_, J64, PF64, PW64, pmn, pmx);
  hipLaunchKernelGGL(k_final,  dim3(1),      dim3(1024), 0, stream, J64, PF64, PW64, out);
}

// Round 12
// 123.816 us; speedup vs baseline: 2.0564x; 2.0564x over previous
//
#include <hip/hip_runtime.h>
#include <hip/hip_bf16.h>
#include <math.h>

#define NVOX   884736      // 96^3 per batch
#define NBINS  64
#define NCHUNK 27648       // NVOX / 32
#define GX     384         // 768 blocks total = 3 blocks/CU (3 waves/SIMD), 1 round
#define NWAVETOT (GX*4)    // 1536 waves/batch -> 18 chunks each, exact
#define NCHW   18          // chunks per wave
#define EPSF   1e-8f

// w = exp(-0.5*((xn-c)/sigma)^2) = exp2(-(A*xn - A*c)^2),  A = sqrt(0.5*log2(e))/sigma
#define A_SC  8.49321957f
#define ABIN  (A_SC/63.0f)

// fixed-point scale for deterministic integer accumulation
#define FSCALE 1073741824.0f   // 2^30
#define DSCALE (1.0/1073741824.0)

typedef __attribute__((ext_vector_type(8))) short short8;
typedef __attribute__((ext_vector_type(4))) float f32x4;
typedef unsigned long long u64;

#define EXP2(x) __builtin_amdgcn_exp2f(x)

#define NJ64 8448   // 2*4096 J + 2*64 PF + 2*64 PW

__device__ __forceinline__ short tobf(float w){
  __bf16 hb = (__bf16)w;
  return __builtin_bit_cast(short, hb);
}

// ---- k_minmax: exact per-block min/max partials (no atomics, no init) + zero u64 region ----
__global__ __launch_bounds__(256) void k_minmax(const float* __restrict__ fixed_,
                                                const float* __restrict__ warped_,
                                                float* __restrict__ pmn,
                                                float* __restrict__ pmx,
                                                u64* __restrict__ w64){
  const int slot = blockIdx.y;                 // img*2 + b
  const int tid  = threadIdx.x;
  if (slot == 0){
    int gid = blockIdx.x*256 + tid;            // 128*256 = 32768 >= 8448
    if (gid < NJ64) w64[gid] = 0ull;
  }
  const float* p = ((slot & 2) ? warped_ : fixed_) + (slot & 1) * NVOX;
  const float4* p4 = (const float4*)p;
  const int n4 = NVOX/4;
  float lo = 3.4e38f, hi = -3.4e38f;
  for (int i = blockIdx.x*256 + tid; i < n4; i += 128*256){
    float4 v = p4[i];
    lo = fminf(lo, fminf(fminf(v.x,v.y), fminf(v.z,v.w)));
    hi = fmaxf(hi, fmaxf(fmaxf(v.x,v.y), fmaxf(v.z,v.w)));
  }
  #pragma unroll
  for (int d = 1; d < 64; d <<= 1){
    lo = fminf(lo, __shfl_xor(lo, d));
    hi = fmaxf(hi, __shfl_xor(hi, d));
  }
  __shared__ float smn[4], smx[4];
  if ((tid & 63) == 0){ smn[tid>>6] = lo; smx[tid>>6] = hi; }
  __syncthreads();
  if (tid == 0){
    pmn[slot*128 + blockIdx.x] = fminf(fminf(smn[0],smn[1]), fminf(smn[2],smn[3]));
    pmx[slot*128 + blockIdx.x] = fmaxf(fmaxf(smx[0],smx[1]), fmaxf(smx[2],smx[3]));
  }
}

// S-loop: FROZEN R4/R5/R9/R10 numerics (t first, then square; 4 independent partials)
__device__ __forceinline__ void s_and_lg(float u, float H, float& lg){
  float S0=0.f, S1=0.f, S2=0.f, S3=0.f;
  #pragma unroll
  for (int k = 0; k < 64; k += 4){
    float t0 = u - (float)(k+0)*H; S0 += EXP2(-(t0*t0));
    float t1 = u - (float)(k+1)*H; S1 += EXP2(-(t1*t1));
    float t2 = u - (float)(k+2)*H; S2 += EXP2(-(t2*t2));
    float t3 = u - (float)(k+3)*H; S3 += EXP2(-(t3*t3));
  }
  const float S = (S0+S1)+(S2+S3);
  lg = -__builtin_amdgcn_logf(S + EPSF);  // log2(1/(S+eps))
}

__global__ __launch_bounds__(256, 3) void k_main(const float* __restrict__ fx0,
                                                 const float* __restrict__ wx0,
                                                 u64* __restrict__ J64,
                                                 u64* __restrict__ PF64,
                                                 u64* __restrict__ PW64,
                                                 const float* __restrict__ pmn,
                                                 const float* __restrict__ pmx){
  const int b    = blockIdx.y;
  const int lane = threadIdx.x & 63;
  const int wid  = threadIdx.x >> 6;
  const int r    = lane & 15;       // bin-within-quadrant (A row / B col)
  const int g    = lane >> 4;       // k-group: voxels 8g..8g+7

  // per-lane min/max from 128 exact partials (lanes 0-31: fixed, 32-63: warped)
  const int hl = lane & 31;
  const int sbase = ((lane >> 5)*2 + b) * 128;
  float lo = fminf(fminf(pmn[sbase+hl], pmn[sbase+32+hl]),
                   fminf(pmn[sbase+64+hl], pmn[sbase+96+hl]));
  float hi = fmaxf(fmaxf(pmx[sbase+hl], pmx[sbase+32+hl]),
                   fmaxf(pmx[sbase+64+hl], pmx[sbase+96+hl]));
  #pragma unroll
  for (int d = 1; d < 32; d <<= 1){           // reduce within each 32-lane half
    lo = fminf(lo, __shfl_xor(lo, d));
    hi = fmaxf(hi, __shfl_xor(hi, d));
  }
  const float mn = lo;
  const float sc = A_SC / (hi - lo + EPSF);

  const float H = ABIN;
  float CQ[4];
  #pragma unroll
  for (int q = 0; q < 4; q++) CQ[q] = (float)(16*q + r) * H;

  f32x4 acc[4][4];
  #pragma unroll
  for (int q = 0; q < 4; q++)
    #pragma unroll
    for (int t = 0; t < 4; t++)
      acc[q][t] = (f32x4){0.f,0.f,0.f,0.f};
  float pfa[4] = {0.f,0.f,0.f,0.f}, pwa[4] = {0.f,0.f,0.f,0.f};

  const float* fx = fx0 + b*NVOX;
  const float* wx = wx0 + b*NVOX;
  const float* src = (lane < 32) ? fx : (wx - 32);
  const int gwave = blockIdx.x*4 + wid;
  const int base0 = gwave*32 + lane;   // chunk stride = NWAVETOT*32 = 49152 elements

  // per-wave LDS scratch for (u, lg) cross-lane distribution (broadcast reads)
  __shared__ float2 sUL[4][64];
  float2* ul = sUL[wid];

  // ---- prologue: chunk 0 current state, chunk 1 raw prefetched ----
  float u_c, lg_c;
  {
    float x0 = src[base0];
    u_c = (x0 - mn) * sc;
    s_and_lg(u_c, H, lg_c);
  }
  float x_n = src[base0 + NWAVETOT*32];

  #pragma unroll 1
  for (int t = 0; t < NCHW; t++){
    short8 Af[4], Bf[4];
    float u_n, lg_n, x_n2;

    // ---- publish own (u,lg); read all 16 needed pairs (broadcast, conflict-free) ----
    ul[lane] = (float2){u_c, lg_c};            // same-wave DS: in-order, no barrier
    float uf[8], lf[8], uw[8], lw[8];
    #pragma unroll
    for (int i = 0; i < 8; i++){
      float2 a = ul[8*g + i];
      float2 c = ul[32 + 8*g + i];
      uf[i] = a.x; lf[i] = a.y;
      uw[i] = c.x; lw[i] = c.y;
    }

    // ---- stage 2: prefetch + next-chunk S while LDS reads are in flight ----
    if (t + 2 < NCHW) x_n2 = src[base0 + (t+2)*(NWAVETOT*32)];
    if (t + 1 < NCHW){
      u_n = (x_n - mn) * sc;
      s_and_lg(u_n, H, lg_n);
    }

    // ---- consume: FROZEN weight form, same accumulation order (i asc, q inner) ----
    #pragma unroll
    for (int i = 0; i < 8; i++){
      #pragma unroll
      for (int q = 0; q < 4; q++){
        float ta = uf[i] - CQ[q];
        float wa = EXP2(__builtin_fmaf(-ta, ta, lf[i]));
        pfa[q] += wa;  Af[q][i] = tobf(wa);
        float tb = uw[i] - CQ[q];
        float wb = EXP2(__builtin_fmaf(-tb, tb, lw[i]));
        pwa[q] += wb;  Bf[q][i] = tobf(wb);
      }
    }

    // ---- 16 MFMAs ----
    #pragma unroll
    for (int q = 0; q < 4; q++)
      #pragma unroll
      for (int qq = 0; qq < 4; qq++)
        acc[q][qq] = __builtin_amdgcn_mfma_f32_16x16x32_bf16(Af[q], Bf[qq], acc[q][qq], 0, 0, 0);

    u_c = u_n; lg_c = lg_n; x_n = x_n2;
  }

  // marginals: shuffle-reduce (deterministic), lanes 0-15 commit as u64 fixed-point
  #pragma unroll
  for (int q = 0; q < 4; q++){
    pfa[q] += __shfl_xor(pfa[q], 16); pfa[q] += __shfl_xor(pfa[q], 32);
    pwa[q] += __shfl_xor(pwa[q], 16); pwa[q] += __shfl_xor(pwa[q], 32);
  }
  if (lane < 16){
    #pragma unroll
    for (int q = 0; q < 4; q++){
      long long vf = __builtin_llrintf(pfa[q] * FSCALE);
      long long vw = __builtin_llrintf(pwa[q] * FSCALE);
      atomicAdd(&PF64[b*64 + 16*q + r], (u64)vf);
      atomicAdd(&PW64[b*64 + 16*q + r], (u64)vw);
    }
  }

  // joint: deterministic block reduce — waves accumulate into jl in FIXED order
  __shared__ float jl[64*64];
  // C/D layout (m89-verified): col = lane&15, row = (lane>>4)*4 + reg
  #pragma unroll
  for (int w2 = 0; w2 < 4; w2++){
    if (wid == w2){
      #pragma unroll
      for (int q = 0; q < 4; q++)
        #pragma unroll
        for (int qq = 0; qq < 4; qq++)
          #pragma unroll
          for (int j = 0; j < 4; j++){
            int idx = (16*q + 4*g + j)*64 + 16*qq + r;
            float v = acc[q][qq][j];
            jl[idx] = (w2 == 0) ? v : (jl[idx] + v);
          }
    }
    __syncthreads();
  }
  // convert to u64 fixed-point, order-independent global accumulation
  for (int i = threadIdx.x; i < 4096; i += 256){
    long long v = __builtin_llrintf(jl[i] * FSCALE);
    if (v) atomicAdd(&J64[b*4096 + i], (u64)v);
  }
}

// ---- k_final: both batches in parallel half-blocks; fp64 accumulate, f32-ratio + hw log ----
__global__ __launch_bounds__(1024) void k_final(const u64* __restrict__ J64,
                                                const u64* __restrict__ PF64,
                                                const u64* __restrict__ PW64,
                                                float* out){
  __shared__ double red[1024];
  const int tid = threadIdx.x;
  const int b   = tid >> 9;          // threads 0-511: batch 0; 512-1023: batch 1
  const int t5  = tid & 511;
  const double invN = 1.0 / (double)NVOX;
  const u64* J  = J64  + b*4096;
  const u64* PF = PF64 + b*64;
  const u64* PW = PW64 + b*64;

  double ts = 0.0;
  for (int i = t5; i < 4096; i += 512) ts += (double)J[i];
  red[tid] = ts; __syncthreads();
  #pragma unroll
  for (int s = 256; s > 0; s >>= 1){ if (t5 < s) red[tid] += red[tid+s]; __syncthreads(); }
  const double tot = red[b << 9] * DSCALE * invN;
  const double cj  = DSCALE * invN / (tot + 1e-8);
  __syncthreads();

  double part = 0.0;
  for (int i = t5; i < 4096; i += 512){
    int k = i >> 6, l = i & 63;
    double pj = (double)J[i] * cj;
    double pp = ((double)PF[k] * DSCALE * invN) * ((double)PW[l] * DSCALE * invN);
    float ratio = (float)((pj + 1e-8) / (pp + 1e-8));
    part += pj * (0.6931471805599453 * (double)__builtin_amdgcn_logf(ratio));
  }
  red[tid] = part; __syncthreads();
  #pragma unroll
  for (int s = 256; s > 0; s >>= 1){ if (t5 < s) red[tid] += red[tid+s]; __syncthreads(); }
  if (tid == 0) out[0] = (float)(-((red[0] + red[512]) * 0.5));
}

extern "C" void kernel_launch(void* const* d_in, const int* in_sizes, int n_in,
                              void* d_out, int out_size, void* d_ws, size_t ws_size,
                              hipStream_t stream) {
  const float* fixed_  = (const float*)d_in[0];
  const float* warped_ = (const float*)d_in[1];
  u64*   w64  = (u64*)d_ws;
  u64*   J64  = w64;              // 2*4096
  u64*   PF64 = w64 + 8192;       // 2*64
  u64*   PW64 = w64 + 8320;       // 2*64
  float* pmn  = (float*)((char*)d_ws + NJ64*8);   // 4*128 floats
  float* pmx  = pmn + 512;
  float* out  = (float*)d_out;

  hipLaunchKernelGGL(k_minmax, dim3(128, 4), dim3(256),  0, stream, fixed_, warped_, pmn, pmx, w64);
  hipLaunchKernelGGL(k_main,   dim3(GX, 2),  dim3(256),  0, stream, fixed_, warped_, J64, PF64, PW64, pmn, pmx);
  hipLaunchKernelGGL(k_final,  dim3(1),      dim3(1024), 0, stream, J64, PF64, PW64, out);
}